// Round 6
// baseline (45.011 us; speedup 1.0000x reference)
//
#include <hip/hip_runtime.h>
#include <hip/hip_bf16.h>

// Problem constants (from reference): B=8192, MN=64*64=4096, D=128
#define NB   8192
#define NMN  4096
#define ND   128

typedef __attribute__((ext_vector_type(8))) short bf16x8;  // 8 bf16 = 16 B
typedef __attribute__((ext_vector_type(8))) short short8;
typedef __attribute__((ext_vector_type(4))) float f32x4;

// ---------------------------------------------------------------------------
// FUSED kernel: per 128x128 output tile, one block:
//   phase 1: load fp32 A/W tiles (coalesced), convert to bf16, store to LDS
//            in packed-fragment layout with XOR swizzle; row norms on the fly.
//            LDS chunk (16B = 8 bf16 along K):  c = panel*256 + q*16 + (r ^ q)
//            (panel = row>>4, r = row&15, q = k-chunk 0..15). The r^q swizzle
//            makes both ds_write_b128 (lanes: rof 0..3 x q 0..15) and
//            ds_read_b128 (lanes: l4 -> q, l15 -> r) uniform across bank quads.
//   phase 2: 4 kk-steps of mfma_f32_16x16x32_bf16, fragments from LDS.
//            Operands swapped (weights = MFMA A-op) so each lane's 4 acc regs
//            are 4 consecutive output columns.
//   phase 3: per-wave LDS transpose (reusing the A buffer) -> 256B-contiguous
//            nontemporal stores (round-4 best store config).
// One dispatch total: removes prep launch + inter-kernel drain.
// ---------------------------------------------------------------------------
__global__ __launch_bounds__(256) void som_fused(const float* __restrict__ batch,
                                                 const float* __restrict__ weights,
                                                 float* __restrict__ out) {
    // XCD-aware swizzle: 2048 blocks, 8 XCDs, 256 blocks per XCD chunk
    const int bx = blockIdx.x;
    const int w  = (bx & 7) * 256 + (bx >> 3);
    const int brow = (w >> 5) << 7;   // 64 row-blocks (batch)
    const int bcol = (w & 31) << 7;   // 32 col-blocks (weights)

    const int tid  = threadIdx.x;
    const int lane = tid & 63;
    const int wid  = tid >> 6;
    const int wr   = wid >> 1;         // wave row (batch dim) 0..1
    const int wc   = wid & 1;          // wave col (weight dim) 0..1
    const int l15  = lane & 15;
    const int l4   = lane >> 4;

    __shared__ __attribute__((aligned(16))) short8 albuf[2048];  // 32 KB A tile
    __shared__ __attribute__((aligned(16))) short8 wlbuf[2048];  // 32 KB W tile
    __shared__ float normsA[128];
    __shared__ float normsW[128];

    // ---- phase 1: convert tiles into LDS (each wave: 8 row-quads per tile) ----
    const int rof = lane >> 4;   // row within quad
    const int q   = lane & 15;   // 16B k-chunk (8 floats)

    #pragma unroll
    for (int i = 0; i < 8; ++i) {
        const int quad = wid + 4 * i;        // 0..31
        const int row  = quad * 4 + rof;     // tile row 0..127

        // A tile
        {
            const float* src = batch + (size_t)(brow + row) * ND + q * 8;
            const f32x4 v0 = *reinterpret_cast<const f32x4*>(src);
            const f32x4 v1 = *reinterpret_cast<const f32x4*>(src + 4);
            __hip_bfloat16 tmp[8];
            tmp[0] = __float2bfloat16(v0.x); tmp[1] = __float2bfloat16(v0.y);
            tmp[2] = __float2bfloat16(v0.z); tmp[3] = __float2bfloat16(v0.w);
            tmp[4] = __float2bfloat16(v1.x); tmp[5] = __float2bfloat16(v1.y);
            tmp[6] = __float2bfloat16(v1.z); tmp[7] = __float2bfloat16(v1.w);
            const int r15 = row & 15;
            albuf[(row >> 4) * 256 + q * 16 + (r15 ^ q)] =
                *reinterpret_cast<short8*>(tmp);
            float p = v0.x * v0.x + v0.y * v0.y + v0.z * v0.z + v0.w * v0.w
                    + v1.x * v1.x + v1.y * v1.y + v1.z * v1.z + v1.w * v1.w;
            #pragma unroll
            for (int off = 1; off < 16; off <<= 1) p += __shfl_xor(p, off, 64);
            if (q == 0) normsA[row] = p;
        }
        // W tile
        {
            const float* src = weights + (size_t)(bcol + row) * ND + q * 8;
            const f32x4 v0 = *reinterpret_cast<const f32x4*>(src);
            const f32x4 v1 = *reinterpret_cast<const f32x4*>(src + 4);
            __hip_bfloat16 tmp[8];
            tmp[0] = __float2bfloat16(v0.x); tmp[1] = __float2bfloat16(v0.y);
            tmp[2] = __float2bfloat16(v0.z); tmp[3] = __float2bfloat16(v0.w);
            tmp[4] = __float2bfloat16(v1.x); tmp[5] = __float2bfloat16(v1.y);
            tmp[6] = __float2bfloat16(v1.z); tmp[7] = __float2bfloat16(v1.w);
            const int r15 = row & 15;
            wlbuf[(row >> 4) * 256 + q * 16 + (r15 ^ q)] =
                *reinterpret_cast<short8*>(tmp);
            float p = v0.x * v0.x + v0.y * v0.y + v0.z * v0.z + v0.w * v0.w
                    + v1.x * v1.x + v1.y * v1.y + v1.z * v1.z + v1.w * v1.w;
            #pragma unroll
            for (int off = 1; off < 16; off <<= 1) p += __shfl_xor(p, off, 64);
            if (q == 0) normsW[row] = p;
        }
    }

    __syncthreads();

    // ---- phase 2: MFMA from LDS ----
    f32x4 acc[4][4];   // [m = batch frag][n = weight frag]
    #pragma unroll
    for (int m = 0; m < 4; ++m)
        #pragma unroll
        for (int n = 0; n < 4; ++n)
            acc[m][n] = (f32x4){0.f, 0.f, 0.f, 0.f};

    #pragma unroll
    for (int kk = 0; kk < 4; ++kk) {
        const int qq = kk * 4 + l4;
        const int sw = l15 ^ qq;
        bf16x8 bat[4], wgt[4];
        #pragma unroll
        for (int m = 0; m < 4; ++m)
            bat[m] = (bf16x8)albuf[(wr * 4 + m) * 256 + qq * 16 + sw];
        #pragma unroll
        for (int n = 0; n < 4; ++n)
            wgt[n] = (bf16x8)wlbuf[(wc * 4 + n) * 256 + qq * 16 + sw];
        #pragma unroll
        for (int m = 0; m < 4; ++m)
            #pragma unroll
            for (int n = 0; n < 4; ++n)
                acc[m][n] = __builtin_amdgcn_mfma_f32_16x16x32_bf16(wgt[n], bat[m], acc[m][n], 0, 0, 0);
    }

    // norms for epilogue (separate LDS arrays, safe to read any time)
    float a2v[4];
    #pragma unroll
    for (int m = 0; m < 4; ++m) a2v[m] = normsA[wr * 64 + m * 16 + l15];
    f32x4 b2v[4];
    #pragma unroll
    for (int n = 0; n < 4; ++n)
        b2v[n] = *reinterpret_cast<const f32x4*>(&normsW[wc * 64 + n * 16 + l4 * 4]);

    // ---- phase 3: epilogue, reusing albuf as the transpose strip ----
    __syncthreads();   // all waves done reading albuf/wlbuf fragments

    f32x4* strip16 = reinterpret_cast<f32x4*>(albuf) + wid * 256;  // 4 KB/wave

    const size_t orow_base = (size_t)(brow + wr * 64);
    const int    ocol      = bcol + wc * 64 + l15 * 4;

    #pragma unroll
    for (int m = 0; m < 4; ++m) {
        // stage: strip[row=l15][chunk = (n*4+l4) ^ l15]  (16B chunks)
        #pragma unroll
        for (int n = 0; n < 4; ++n) {
            f32x4 val = a2v[m] + b2v[n] - 2.0f * acc[m][n];
            strip16[l15 * 16 + ((n * 4 + l4) ^ l15)] = val;
        }
        // drain: row r = 4j + l4, chunk l15 stored at l15 ^ r
        #pragma unroll
        for (int j = 0; j < 4; ++j) {
            const int r = 4 * j + l4;
            f32x4 val = strip16[r * 16 + (l15 ^ r)];
            __builtin_nontemporal_store(val,
                reinterpret_cast<f32x4*>(out + (orow_base + m * 16 + r) * NMN + ocol));
        }
    }
}

// ---------------------------------------------------------------------------
extern "C" void kernel_launch(void* const* d_in, const int* in_sizes, int n_in,
                              void* d_out, int out_size, void* d_ws, size_t ws_size,
                              hipStream_t stream) {
    const float* batch   = (const float*)d_in[0];   // (8192, 128) fp32
    const float* weights = (const float*)d_in[1];   // (4096, 128) fp32
    float* out = (float*)d_out;                     // (8192, 4096) fp32

    // single fused dispatch: 64 row-blocks * 32 col-blocks = 2048 blocks
    som_fused<<<dim3(2048), dim3(256), 0, stream>>>(batch, weights, out);
}

// Round 7
// 42.217 us; speedup vs baseline: 1.0662x; 1.0662x over previous
//
#include <hip/hip_runtime.h>
#include <hip/hip_bf16.h>

// Problem constants (from reference): B=8192, MN=64*64=4096, D=128
#define NB   8192
#define NMN  4096
#define ND   128

typedef __attribute__((ext_vector_type(8))) short bf16x8;  // 8 bf16 = 16 B
typedef __attribute__((ext_vector_type(8))) short short8;
typedef __attribute__((ext_vector_type(4))) float f32x4;

// ---------------------------------------------------------------------------
// Packed fragment layout for MFMA operands:
//   array viewed in 16B chunks: chunk_idx = (row>>4)*256 + q*16 + (row&15)
// where q = 16B k-chunk (8 bf16 along K), row = matrix row.
// A wave's fragment load (fixed panel, fixed kk) reads chunks
//   base + l4*16 + l15  -> 64 consecutive 16B chunks = 1 KB contiguous.
// ---------------------------------------------------------------------------

// Prep: fp32 -> bf16 packed layout + exact fp32 row-norms.
__global__ __launch_bounds__(256) void som_prep(const float* __restrict__ batch,
                                                const float* __restrict__ weights,
                                                __hip_bfloat16* __restrict__ apk,
                                                __hip_bfloat16* __restrict__ wpk,
                                                float* __restrict__ a2,
                                                float* __restrict__ b2) {
    const int wid  = threadIdx.x >> 6;
    const int lane = threadIdx.x & 63;
    const int rof  = lane >> 4;    // row within wave's 4-row group
    const int q    = lane & 15;    // 16B k-chunk index (8 floats)

    int row = blockIdx.x * 16 + wid * 4 + rof;   // 768 blocks * 16 rows

    const float* src;
    __hip_bfloat16* dst;
    float* norm;
    if (row < NB) {
        src = batch;  dst = apk; norm = a2;
    } else {
        row -= NB;
        src = weights; dst = wpk; norm = b2;
    }

    const f32x4 v0 = *reinterpret_cast<const f32x4*>(src + (size_t)row * ND + q * 8);
    const f32x4 v1 = *reinterpret_cast<const f32x4*>(src + (size_t)row * ND + q * 8 + 4);

    __hip_bfloat16 tmp[8];
    tmp[0] = __float2bfloat16(v0.x); tmp[1] = __float2bfloat16(v0.y);
    tmp[2] = __float2bfloat16(v0.z); tmp[3] = __float2bfloat16(v0.w);
    tmp[4] = __float2bfloat16(v1.x); tmp[5] = __float2bfloat16(v1.y);
    tmp[6] = __float2bfloat16(v1.z); tmp[7] = __float2bfloat16(v1.w);

    const int chunk = (row >> 4) * 256 + q * 16 + (row & 15);
    *reinterpret_cast<short8*>(dst + (size_t)chunk * 8) =
        *reinterpret_cast<short8*>(tmp);

    float p = v0.x * v0.x + v0.y * v0.y + v0.z * v0.z + v0.w * v0.w
            + v1.x * v1.x + v1.y * v1.y + v1.z * v1.z + v1.w * v1.w;
    #pragma unroll
    for (int off = 1; off < 16; off <<= 1) p += __shfl_xor(p, off, 64);
    if (q == 0) norm[row] = p;
}

// ---------------------------------------------------------------------------
// GEMM: out[b][w] = a2[b] + b2[w] - 2 * dot(A[b], W[w])
// 128x128 block tile, 4 waves (2x2), each wave 64(batch) x 64(weight).
// K=128 -> 4 k-steps of mfma_f32_16x16x32_bf16, fragments straight from
// L2-resident packed copies (1KB contiguous per load instr, no barriers).
//
// __launch_bounds__(256, 4): force VGPR <= 128 so 4 blocks/CU are resident
// (16 waves/CU). With only 2 blocks/CU the store pipe idles during each
// block's load+MFMA phase (~25% of time) — MLP theory from round-6 analysis.
//
// Epilogue: per-wave LDS transpose -> 256B-contiguous nontemporal stores
// (round-4 best store config).
// ---------------------------------------------------------------------------
__global__ __launch_bounds__(256, 4) void som_gemm(const __hip_bfloat16* __restrict__ apk_,
                                                   const __hip_bfloat16* __restrict__ wpk_,
                                                   const float* __restrict__ a2,
                                                   const float* __restrict__ b2,
                                                   float* __restrict__ out) {
    // XCD-aware swizzle: 2048 blocks, 8 XCDs, 256 blocks per XCD chunk
    const int bx = blockIdx.x;
    const int w  = (bx & 7) * 256 + (bx >> 3);
    const int brow = (w >> 5) << 7;   // 64 row-blocks (batch)
    const int bcol = (w & 31) << 7;   // 32 col-blocks (weights)

    const int tid  = threadIdx.x;
    const int lane = tid & 63;
    const int wid  = tid >> 6;
    const int wr   = wid >> 1;         // wave row (batch dim) 0..1
    const int wc   = wid & 1;          // wave col (weight dim) 0..1
    const int l15  = lane & 15;
    const int l4   = lane >> 4;

    const bf16x8* A = reinterpret_cast<const bf16x8*>(apk_);
    const bf16x8* W = reinterpret_cast<const bf16x8*>(wpk_);

    const int aoff = ((brow >> 4) + wr * 4) * 256 + l4 * 16 + l15;
    const int woff = ((bcol >> 4) + wc * 4) * 256 + l4 * 16 + l15;

    f32x4 acc[4][4];   // [m = batch frag][n = weight frag]
    #pragma unroll
    for (int m = 0; m < 4; ++m)
        #pragma unroll
        for (int n = 0; n < 4; ++n)
            acc[m][n] = (f32x4){0.f, 0.f, 0.f, 0.f};

    #pragma unroll
    for (int kk = 0; kk < 4; ++kk) {
        bf16x8 bat[4], wgt[4];
        #pragma unroll
        for (int m = 0; m < 4; ++m) bat[m] = A[aoff + m * 256 + kk * 64];
        #pragma unroll
        for (int n = 0; n < 4; ++n) wgt[n] = W[woff + n * 256 + kk * 64];
        #pragma unroll
        for (int m = 0; m < 4; ++m)
            #pragma unroll
            for (int n = 0; n < 4; ++n)
                acc[m][n] = __builtin_amdgcn_mfma_f32_16x16x32_bf16(wgt[n], bat[m], acc[m][n], 0, 0, 0);
    }

    // ---- epilogue ----
    __shared__ float strip[4][16][64];   // 16 KB, one 4KB strip per wave
    f32x4* strip16 = reinterpret_cast<f32x4*>(&strip[wid][0][0]);

    float a2v[4];
    #pragma unroll
    for (int m = 0; m < 4; ++m) a2v[m] = a2[brow + wr * 64 + m * 16 + l15];

    f32x4 b2v[4];
    #pragma unroll
    for (int n = 0; n < 4; ++n)
        b2v[n] = *reinterpret_cast<const f32x4*>(&b2[bcol + wc * 64 + n * 16 + l4 * 4]);

    const size_t orow_base = (size_t)(brow + wr * 64);
    const int    ocol      = bcol + wc * 64 + l15 * 4;

    #pragma unroll
    for (int m = 0; m < 4; ++m) {
        // stage: strip[row=l15][chunk = (n*4+l4) ^ l15]  (16B chunks)
        #pragma unroll
        for (int n = 0; n < 4; ++n) {
            f32x4 val = a2v[m] + b2v[n] - 2.0f * acc[m][n];
            strip16[l15 * 16 + ((n * 4 + l4) ^ l15)] = val;
        }
        // drain: row r = 4j + l4, chunk l15 stored at l15 ^ r
        #pragma unroll
        for (int j = 0; j < 4; ++j) {
            const int r = 4 * j + l4;
            f32x4 val = strip16[r * 16 + (l15 ^ r)];
            __builtin_nontemporal_store(val,
                reinterpret_cast<f32x4*>(out + (orow_base + m * 16 + r) * NMN + ocol));
        }
    }
}

// ---------------------------------------------------------------------------
extern "C" void kernel_launch(void* const* d_in, const int* in_sizes, int n_in,
                              void* d_out, int out_size, void* d_ws, size_t ws_size,
                              hipStream_t stream) {
    const float* batch   = (const float*)d_in[0];   // (8192, 128) fp32
    const float* weights = (const float*)d_in[1];   // (4096, 128) fp32
    float* out = (float*)d_out;                     // (8192, 4096) fp32

    // workspace layout:
    //   a2  : 8192 * 4          =   32768 B @ 0
    //   b2  : 4096 * 4          =   16384 B @ 32768
    //   apk : 8192 * 128 * 2    = 2097152 B @ 49152   (packed fragment layout)
    //   wpk : 4096 * 128 * 2    = 1048576 B @ 2146304
    char* ws = (char*)d_ws;
    float* a2 = (float*)(ws);
    float* b2 = (float*)(ws + 32768);
    __hip_bfloat16* apk = (__hip_bfloat16*)(ws + 49152);
    __hip_bfloat16* wpk = (__hip_bfloat16*)(ws + 49152 + 2097152);

    som_prep<<<dim3((NB + NMN) / 16), dim3(256), 0, stream>>>(batch, weights, apk, wpk, a2, b2);

    som_gemm<<<dim3(2048), dim3(256), 0, stream>>>(apk, wpk, a2, b2, out);
}

// Round 8
// 34.593 us; speedup vs baseline: 1.3012x; 1.2204x over previous
//
#include <hip/hip_runtime.h>
#include <hip/hip_bf16.h>

// Problem constants (from reference): B=8192, MN=64*64=4096, D=128
#define NB   8192
#define NMN  4096
#define ND   128

typedef __attribute__((ext_vector_type(8))) short bf16x8;  // 8 bf16 = 16 B
typedef __attribute__((ext_vector_type(8))) short short8;
typedef __attribute__((ext_vector_type(4))) float f32x4;

// ---------------------------------------------------------------------------
// Packed fragment layout for MFMA operands:
//   array viewed in 16B chunks: chunk_idx = (row>>4)*256 + q*16 + (row&15)
// where q = 16B k-chunk (8 bf16 along K), row = matrix row.
// A wave's fragment load (fixed panel, fixed kk) reads chunks
//   base + l4*16 + l15  -> 64 consecutive 16B chunks = 1 KB contiguous.
// ---------------------------------------------------------------------------

// Prep: fp32 -> bf16 packed layout + exact fp32 row-norms.
__global__ __launch_bounds__(256) void som_prep(const float* __restrict__ batch,
                                                const float* __restrict__ weights,
                                                __hip_bfloat16* __restrict__ apk,
                                                __hip_bfloat16* __restrict__ wpk,
                                                float* __restrict__ a2,
                                                float* __restrict__ b2) {
    const int wid  = threadIdx.x >> 6;
    const int lane = threadIdx.x & 63;
    const int rof  = lane >> 4;    // row within wave's 4-row group
    const int q    = lane & 15;    // 16B k-chunk index (8 floats)

    int row = blockIdx.x * 16 + wid * 4 + rof;   // 768 blocks * 16 rows

    const float* src;
    __hip_bfloat16* dst;
    float* norm;
    if (row < NB) {
        src = batch;  dst = apk; norm = a2;
    } else {
        row -= NB;
        src = weights; dst = wpk; norm = b2;
    }

    const f32x4 v0 = *reinterpret_cast<const f32x4*>(src + (size_t)row * ND + q * 8);
    const f32x4 v1 = *reinterpret_cast<const f32x4*>(src + (size_t)row * ND + q * 8 + 4);

    __hip_bfloat16 tmp[8];
    tmp[0] = __float2bfloat16(v0.x); tmp[1] = __float2bfloat16(v0.y);
    tmp[2] = __float2bfloat16(v0.z); tmp[3] = __float2bfloat16(v0.w);
    tmp[4] = __float2bfloat16(v1.x); tmp[5] = __float2bfloat16(v1.y);
    tmp[6] = __float2bfloat16(v1.z); tmp[7] = __float2bfloat16(v1.w);

    const int chunk = (row >> 4) * 256 + q * 16 + (row & 15);
    *reinterpret_cast<short8*>(dst + (size_t)chunk * 8) =
        *reinterpret_cast<short8*>(tmp);

    float p = v0.x * v0.x + v0.y * v0.y + v0.z * v0.z + v0.w * v0.w
            + v1.x * v1.x + v1.y * v1.y + v1.z * v1.z + v1.w * v1.w;
    #pragma unroll
    for (int off = 1; off < 16; off <<= 1) p += __shfl_xor(p, off, 64);
    if (q == 0) norm[row] = p;
}

// ---------------------------------------------------------------------------
// PERSISTENT GEMM: out[b][w] = a2[b] + b2[w] - 2 * dot(A[b], W[w])
// 512 blocks (2/CU), each processes 4 tiles: t = bx + 512*i.
// Tile swizzle w = (t&7)*256 + (t>>3): stepping t by 512 keeps (t&7) and
// (w&31) constant -> same XCD, SAME weight panel for all 4 tiles; only the
// batch row-band advances (brow += 256). So:
//   * all 16 W fragments are loaded ONCE into VGPRs and reused (-40% reads)
//   * tile i+1's A-loads/MFMA overlap tile i's NT store drain
//   * no __syncthreads anywhere (per-wave LDS strips, in-order DS ops)
// Epilogue per tile: per-wave LDS transpose -> 256B-contiguous NT stores
// (round-4 best store config).
// ---------------------------------------------------------------------------
__global__ __launch_bounds__(256) void som_gemm(const __hip_bfloat16* __restrict__ apk_,
                                                const __hip_bfloat16* __restrict__ wpk_,
                                                const float* __restrict__ a2,
                                                const float* __restrict__ b2,
                                                float* __restrict__ out) {
    const int bx = blockIdx.x;          // 0..511
    const int w0 = (bx & 7) * 256 + (bx >> 3);
    const int bcol = (w0 & 31) << 7;    // constant across this block's tiles

    const int tid  = threadIdx.x;
    const int lane = tid & 63;
    const int wid  = tid >> 6;
    const int wr   = wid >> 1;          // wave row (batch dim) 0..1
    const int wc   = wid & 1;           // wave col (weight dim) 0..1
    const int l15  = lane & 15;
    const int l4   = lane >> 4;

    const bf16x8* A = reinterpret_cast<const bf16x8*>(apk_);
    const bf16x8* W = reinterpret_cast<const bf16x8*>(wpk_);

    __shared__ float strip[4][16][64];   // 16 KB, one 4KB strip per wave
    f32x4* strip16 = reinterpret_cast<f32x4*>(&strip[wid][0][0]);

    // ---- load ALL weight fragments once (fixed panel) ----
    const int woff = ((bcol >> 4) + wc * 4) * 256 + l4 * 16 + l15;
    bf16x8 wgt[4][4];                    // [kk][n]
    #pragma unroll
    for (int kk = 0; kk < 4; ++kk)
        #pragma unroll
        for (int n = 0; n < 4; ++n)
            wgt[kk][n] = W[woff + n * 256 + kk * 64];

    f32x4 b2v[4];
    #pragma unroll
    for (int n = 0; n < 4; ++n)
        b2v[n] = *reinterpret_cast<const f32x4*>(&b2[bcol + wc * 64 + n * 16 + l4 * 4]);

    const int ocol = bcol + wc * 64 + l15 * 4;

    // ---- 4 tiles: brow = ((w0>>5) + 2*i) * 128 ----
    #pragma unroll
    for (int i = 0; i < 4; ++i) {
        const int brow = ((w0 >> 5) + 2 * i) << 7;
        const int aoff = ((brow >> 4) + wr * 4) * 256 + l4 * 16 + l15;

        f32x4 acc[4][4];   // [m = batch frag][n = weight frag]
        #pragma unroll
        for (int m = 0; m < 4; ++m)
            #pragma unroll
            for (int n = 0; n < 4; ++n)
                acc[m][n] = (f32x4){0.f, 0.f, 0.f, 0.f};

        #pragma unroll
        for (int kk = 0; kk < 4; ++kk) {
            bf16x8 bat[4];
            #pragma unroll
            for (int m = 0; m < 4; ++m) bat[m] = A[aoff + m * 256 + kk * 64];
            #pragma unroll
            for (int m = 0; m < 4; ++m)
                #pragma unroll
                for (int n = 0; n < 4; ++n)
                    acc[m][n] = __builtin_amdgcn_mfma_f32_16x16x32_bf16(wgt[kk][n], bat[m], acc[m][n], 0, 0, 0);
        }

        float a2v[4];
        #pragma unroll
        for (int m = 0; m < 4; ++m) a2v[m] = a2[brow + wr * 64 + m * 16 + l15];

        const size_t orow_base = (size_t)(brow + wr * 64);

        #pragma unroll
        for (int m = 0; m < 4; ++m) {
            // stage: strip[row=l15][chunk = (n*4+l4) ^ l15]  (16B chunks)
            #pragma unroll
            for (int n = 0; n < 4; ++n) {
                f32x4 val = a2v[m] + b2v[n] - 2.0f * acc[m][n];
                strip16[l15 * 16 + ((n * 4 + l4) ^ l15)] = val;
            }
            // drain: row r = 4j + l4, chunk l15 stored at l15 ^ r
            #pragma unroll
            for (int j = 0; j < 4; ++j) {
                const int r = 4 * j + l4;
                f32x4 val = strip16[r * 16 + (l15 ^ r)];
                __builtin_nontemporal_store(val,
                    reinterpret_cast<f32x4*>(out + (orow_base + m * 16 + r) * NMN + ocol));
            }
        }
    }
}

// ---------------------------------------------------------------------------
extern "C" void kernel_launch(void* const* d_in, const int* in_sizes, int n_in,
                              void* d_out, int out_size, void* d_ws, size_t ws_size,
                              hipStream_t stream) {
    const float* batch   = (const float*)d_in[0];   // (8192, 128) fp32
    const float* weights = (const float*)d_in[1];   // (4096, 128) fp32
    float* out = (float*)d_out;                     // (8192, 4096) fp32

    // workspace layout:
    //   a2  : 8192 * 4          =   32768 B @ 0
    //   b2  : 4096 * 4          =   16384 B @ 32768
    //   apk : 8192 * 128 * 2    = 2097152 B @ 49152   (packed fragment layout)
    //   wpk : 4096 * 128 * 2    = 1048576 B @ 2146304
    char* ws = (char*)d_ws;
    float* a2 = (float*)(ws);
    float* b2 = (float*)(ws + 32768);
    __hip_bfloat16* apk = (__hip_bfloat16*)(ws + 49152);
    __hip_bfloat16* wpk = (__hip_bfloat16*)(ws + 49152 + 2097152);

    som_prep<<<dim3((NB + NMN) / 16), dim3(256), 0, stream>>>(batch, weights, apk, wpk, a2, b2);

    // persistent: 512 blocks, 4 tiles each (2048 tiles total)
    som_gemm<<<dim3(512), dim3(256), 0, stream>>>(apk, wpk, a2, b2, out);
}